// Round 10
// baseline (137.058 us; speedup 1.0000x reference)
//
#include <hip/hip_runtime.h>
#include <stdint.h>

// DCNv2 forward, MI355X — R21: R20 with the peeled-period register-set fix.
//  R20 failed correctness (absmax 0.855): steady loop ends with FITER_P(33,
//  GI=gB) => period-35 gathers live in gB, but peeled P=34 consumed gA
//  (stale period-34 data). Fix: peeled P=34 bilin consumes gB. All other
//  structure identical to R20:
//   - BK=64 periods (36 barriers), counted vmcnt: issue B(P)x4 + G(P+2)x8
//     per period; vmcnt(12) before bilin, vmcnt(8) before 16 MFMA;
//     lgkm-only barrier; 8 loads always in flight.
//   - As[2][64][64] XOR-swizzled (c ^= (row&7)<<3) — conflict-free b128.
//  K0 prep_and_transpose, K1 offset_conv_sk, K2 index_prep unchanged.

#define CIN 256
#define COUT 256
#define HWS 4096      // H*W
#define MTOT 16384    // B*H*W
#define KTOT 2304     // CIN*9
#define SPLITK 8

typedef __attribute__((ext_vector_type(8))) short bf16x8;
typedef __attribute__((ext_vector_type(4))) float f32x4;

__device__ __forceinline__ unsigned short f2bf(float f) {
  unsigned int u = __float_as_uint(f);
  unsigned int r = (u + 0x7fffu + ((u >> 16) & 1u)) >> 16;
  return (unsigned short)r;
}
__device__ __forceinline__ float bf2f(unsigned short u) {
  return __uint_as_float(((unsigned int)u) << 16);
}
// bf16 pair unpack: 1 VALU each.
__device__ __forceinline__ float bflo(unsigned int u) { return __uint_as_float(u << 16); }
__device__ __forceinline__ float bfhi(unsigned int u) { return __uint_as_float(u & 0xffff0000u); }

__device__ __forceinline__ void gload_lds16(const void* g, void* l) {
  __builtin_amdgcn_global_load_lds((const __attribute__((address_space(1))) void*)g,
                                   (__attribute__((address_space(3))) void*)l, 16, 0, 0);
}

// Issue-pinned loads; completion via manual counted s_waitcnt + sched fence.
#define GLOAD8(D, P)  asm volatile("global_load_dwordx2 %0, %1, off" : "=v"(D) : "v"(P))
#define GLOAD16(D, P) asm volatile("global_load_dwordx4 %0, %1, off" : "=v"(D) : "v"(P))
#define WAITVM(N)                                            \
  {                                                          \
    asm volatile("s_waitcnt vmcnt(" #N ")" ::: "memory");    \
    __builtin_amdgcn_sched_barrier(0);                       \
  }
#define BARRIER_LGKM                                                  \
  { asm volatile("s_waitcnt lgkmcnt(0)\n\ts_barrier" ::: "memory"); }

// As column swizzle: applied identically on write and read.
#define ASW(c, rr) ((c) ^ (((rr) & 7) << 3))

// ---------------- K0: fused transpose + weight prep (WB2 frag-block order) ----------------
__global__ __launch_bounds__(256) void prep_and_transpose(const float* __restrict__ x,
                                                          const float* __restrict__ w,
                                                          const float* __restrict__ pw,
                                                          unsigned short* __restrict__ xt,
                                                          unsigned short* __restrict__ WB,
                                                          unsigned short* __restrict__ PWs,
                                                          unsigned short* __restrict__ zerop) {
  __shared__ float tile[32][33];
  int bid = blockIdx.x;
  if (bid < 4096) {
    int b = bid >> 10;
    int rest = bid & 1023;
    int hw0 = (rest & 127) * 32;
    int c0 = ((rest >> 7) & 7) * 32;
    int tx = threadIdx.x & 31, ty = threadIdx.x >> 5;
    for (int i = ty; i < 32; i += 8)
      tile[i][tx] = x[(size_t)(b * CIN + c0 + i) * HWS + hw0 + tx];
    __syncthreads();
    for (int r = ty; r < 32; r += 8)
      xt[(size_t)(b * HWS + hw0 + r) * CIN + c0 + tx] = f2bf(tile[tx][r]);
  } else {
    int idx = (bid - 4096) * 256 + threadIdx.x;
    if (idx < 512)
      *(uint4*)(zerop + idx * 8) = make_uint4(0, 0, 0, 0);
    if (idx < KTOT * COUT) {
      // WB2[t][j][quad][row][8]: f = (((t*16+j)*4+quad)*16+row)*8+e
      int f = idx;
      int e = f & 7;
      int row = (f >> 3) & 15;
      int quad = (f >> 7) & 3;
      int j = (f >> 9) & 15;
      int t = f >> 13;                 // 0..71
      int kk = t * 32 + quad * 8 + e;
      int o = j * 16 + row;
      int k = kk >> 8, c = kk & 255;
      WB[f] = f2bf(w[o * KTOT + c * 9 + k]);
    } else {
      int f2 = idx - KTOT * COUT;   // < 2304*32
      int t_ = f2 & 7;
      int rest = f2 >> 3;
      int j = rest & 31;
      int kk = (rest >> 5) * 8 + t_;
      int k = kk >> 8, c = kk & 255;
      float v = (j < 27) ? pw[j * KTOT + c * 9 + k] : 0.0f;
      PWs[f2] = f2bf(v);
    }
  }
}

// ---------------- K1: offset conv, split-K, BM=64 ----------------
__global__ __launch_bounds__(256) void offset_conv_sk(const unsigned short* __restrict__ xt,
                                                      const unsigned short* __restrict__ PWs,
                                                      const unsigned short* __restrict__ zerop,
                                                      float* __restrict__ Pbuf) {
  __shared__ unsigned short Al[64 * 32];   // 4 KB
  __shared__ unsigned short Bl[1024];      // 2 KB
  int tid = threadIdx.x;
  int lane = tid & 63, wv = tid >> 6;
  int mt = (blockIdx.x & 7) * 32 + (blockIdx.x >> 3);   // XCD swizzle
  int m0 = mt * 64;
  int s = blockIdx.y;
  int b = m0 >> 12;
  int hw0 = m0 & 4095;
  f32x4 acc[2] = {};

  for (int tt = 0; tt < 72 / SPLITK; ++tt) {
    int t = s * (72 / SPLITK) + tt;
    int k = t >> 3, c0 = (t & 7) * 32;
    int dyk = k / 3 - 1;
    int dxk = k % 3 - 1;
    __syncthreads();
    if (tid < 128)
      gload_lds16(PWs + (size_t)t * 1024 + tid * 8, &Bl[tid * 8]);
    {
      int r = tid >> 2;
      int hw = hw0 + r;
      int h = hw >> 6, wwp = hw & 63;
      int y = h + dyk, xx = wwp + dxk;
      bool valid = ((unsigned)y < 64u) && ((unsigned)xx < 64u);
      const unsigned short* src = valid
          ? xt + ((size_t)((b << 12) + (y << 6) + xx) << 8) + c0 + (tid & 3) * 8
          : zerop;
      gload_lds16(src, &Al[tid * 8]);
    }
    __syncthreads();
    int row = lane & 15, quad = lane >> 4;
    bf16x8 af = *(const bf16x8*)&Al[(wv * 16 + row) * 32 + quad * 8];
    for (int j = 0; j < 2; ++j) {
      bf16x8 bfr = *(const bf16x8*)&Bl[(quad * 32 + j * 16 + row) * 8];
      acc[j] = __builtin_amdgcn_mfma_f32_16x16x32_bf16(af, bfr, acc[j], 0, 0, 0);
    }
  }

  int row = lane & 15, quad = lane >> 4;
  for (int j = 0; j < 2; ++j) {
    int n = j * 16 + row;
    for (int r_ = 0; r_ < 4; ++r_) {
      int m = m0 + wv * 16 + quad * 4 + r_;
      Pbuf[((size_t)s * MTOT + m) * 32 + n] = acc[j][r_];
    }
  }
}

// ---------------- K2: index prep — reduce Pbuf, compute corner idx + weights ----------------
__global__ __launch_bounds__(256) void index_prep(const float* __restrict__ Pbuf,
                                                  const float* __restrict__ p_bias,
                                                  int4* __restrict__ DIW) {
  int gid = blockIdx.x * 256 + threadIdx.x;   // 0..147455 == 16384*9
  int m = gid / 9;
  int k = gid - m * 9;

  float dy = p_bias[2 * k];
  float dx = p_bias[2 * k + 1];
  float mv = p_bias[18 + k];
#pragma unroll
  for (int s = 0; s < SPLITK; ++s) {
    const float* p = Pbuf + ((size_t)s * MTOT + m) * 32;
    dy += p[2 * k];
    dx += p[2 * k + 1];
    mv += p[18 + k];
  }
  float mk = 1.0f / (1.0f + __expf(-mv));

  int hw = m & 4095, h = hw >> 6, ww = hw & 63;
  float py = (float)(h - 1 + k / 3) + dy;
  float px = (float)(ww - 1 + k % 3) + dx;
  float y0f = floorf(py), x0f = floorf(px);
  float ay = py - y0f, ax = px - x0f;
  int y0 = (int)y0f, x0 = (int)x0f;

  float w00 = (1.f - ay) * (1.f - ax) * mk;
  float w01 = (1.f - ay) * ax * mk;
  float w10 = ay * (1.f - ax) * mk;
  float w11 = ay * ax * mk;

  float vy0 = ((unsigned)y0 < 64u) ? 1.f : 0.f;
  float vy1 = ((unsigned)(y0 + 1) < 64u) ? 1.f : 0.f;
  float vx0 = ((unsigned)x0 < 64u) ? 1.f : 0.f;
  float vx1 = ((unsigned)(x0 + 1) < 64u) ? 1.f : 0.f;
  w00 *= vy0 * vx0; w01 *= vy0 * vx1; w10 *= vy1 * vx0; w11 *= vy1 * vx1;

  int yc0 = min(max(y0, 0), 63), yc1 = min(max(y0 + 1, 0), 63);
  int xc0 = min(max(x0, 0), 63), xc1 = min(max(x0 + 1, 0), 63);

  DIW[(size_t)gid * 2] = make_int4((yc0 * 64 + xc0) * 256, (yc0 * 64 + xc1) * 256,
                                   (yc1 * 64 + xc0) * 256, (yc1 * 64 + xc1) * 256);
  float4 w4 = make_float4(w00, w01, w10, w11);
  ((float4*)DIW)[(size_t)gid * 2 + 1] = w4;
}

// ---------------- K3: fused sample + GEMM — BK=64 counted-vmcnt pipeline ----------------
__device__ __forceinline__ void bilin4p(const uint2 c00, const uint2 c01,
                                        const uint2 c10, const uint2 c11,
                                        const float4 w4, unsigned short* dst) {
  float v0 = w4.x * bflo(c00.x) + w4.y * bflo(c01.x) + w4.z * bflo(c10.x) + w4.w * bflo(c11.x);
  float v1 = w4.x * bfhi(c00.x) + w4.y * bfhi(c01.x) + w4.z * bfhi(c10.x) + w4.w * bfhi(c11.x);
  float v2 = w4.x * bflo(c00.y) + w4.y * bflo(c01.y) + w4.z * bflo(c10.y) + w4.w * bflo(c11.y);
  float v3 = w4.x * bfhi(c00.y) + w4.y * bfhi(c01.y) + w4.z * bfhi(c10.y) + w4.w * bfhi(c11.y);
  ushort4 o;
  o.x = f2bf(v0); o.y = f2bf(v1); o.z = f2bf(v2); o.w = f2bf(v3);
  *(ushort4*)dst = o;
}

#define MFMA16P                                                                          \
  acc[0][0] = __builtin_amdgcn_mfma_f32_16x16x32_bf16(afr0, bB0, acc[0][0], 0, 0, 0);    \
  acc[0][1] = __builtin_amdgcn_mfma_f32_16x16x32_bf16(afr0, bB1, acc[0][1], 0, 0, 0);    \
  acc[1][0] = __builtin_amdgcn_mfma_f32_16x16x32_bf16(afr1, bB0, acc[1][0], 0, 0, 0);    \
  acc[1][1] = __builtin_amdgcn_mfma_f32_16x16x32_bf16(afr1, bB1, acc[1][1], 0, 0, 0);    \
  acc[2][0] = __builtin_amdgcn_mfma_f32_16x16x32_bf16(afr2, bB0, acc[2][0], 0, 0, 0);    \
  acc[2][1] = __builtin_amdgcn_mfma_f32_16x16x32_bf16(afr2, bB1, acc[2][1], 0, 0, 0);    \
  acc[3][0] = __builtin_amdgcn_mfma_f32_16x16x32_bf16(afr3, bB0, acc[3][0], 0, 0, 0);    \
  acc[3][1] = __builtin_amdgcn_mfma_f32_16x16x32_bf16(afr3, bB1, acc[3][1], 0, 0, 0);    \
  acc[0][0] = __builtin_amdgcn_mfma_f32_16x16x32_bf16(afr4, bB2, acc[0][0], 0, 0, 0);    \
  acc[0][1] = __builtin_amdgcn_mfma_f32_16x16x32_bf16(afr4, bB3, acc[0][1], 0, 0, 0);    \
  acc[1][0] = __builtin_amdgcn_mfma_f32_16x16x32_bf16(afr5, bB2, acc[1][0], 0, 0, 0);    \
  acc[1][1] = __builtin_amdgcn_mfma_f32_16x16x32_bf16(afr5, bB3, acc[1][1], 0, 0, 0);    \
  acc[2][0] = __builtin_amdgcn_mfma_f32_16x16x32_bf16(afr6, bB2, acc[2][0], 0, 0, 0);    \
  acc[2][1] = __builtin_amdgcn_mfma_f32_16x16x32_bf16(afr6, bB3, acc[2][1], 0, 0, 0);    \
  acc[3][0] = __builtin_amdgcn_mfma_f32_16x16x32_bf16(afr7, bB2, acc[3][0], 0, 0, 0);    \
  acc[3][1] = __builtin_amdgcn_mfma_f32_16x16x32_bf16(afr7, bB3, acc[3][1], 0, 0, 0);

// Steady period. GI* receive G for period P+2's data; GC* hold G (issued at
// P-1) carrying period P+1's data, consumed by bilin.
#define FITER_P(P, PAR, GI0, GI1, GI2, GI3, GI4, GI5, GI6, GI7,                          \
                GC0, GC1, GC2, GC3, GC4, GC5, GC6, GC7)                                  \
  {                                                                                      \
    const unsigned short* bt0 = bpb + (size_t)(2 * (P)) * 8192;                          \
    GLOAD16(bB0, bt0);                                                                   \
    GLOAD16(bB1, bt0 + 512);                                                             \
    GLOAD16(bB2, bt0 + 8192);                                                            \
    GLOAD16(bB3, bt0 + 8192 + 512);                                                      \
    if ((((P) + 2) & 3) == 0) dI4 = Tbl[r][((P) + 2) >> 2][0];                           \
    int cb = ((2 * (P) + 4) & 7) * 32 + qo;                                              \
    GLOAD8(GI0, xtb + dI4.x + cb);                                                       \
    GLOAD8(GI1, xtb + dI4.y + cb);                                                       \
    GLOAD8(GI2, xtb + dI4.z + cb);                                                       \
    GLOAD8(GI3, xtb + dI4.w + cb);                                                       \
    GLOAD8(GI4, xtb + dI4.x + cb + 32);                                                  \
    GLOAD8(GI5, xtb + dI4.y + cb + 32);                                                  \
    GLOAD8(GI6, xtb + dI4.z + cb + 32);                                                  \
    GLOAD8(GI7, xtb + dI4.w + cb + 32);                                                  \
    afr0 = *(const bf16x8*)&As[PAR][row][ASW(quad * 8, row)];                            \
    afr1 = *(const bf16x8*)&As[PAR][16 + row][ASW(quad * 8, row)];                       \
    afr2 = *(const bf16x8*)&As[PAR][32 + row][ASW(quad * 8, row)];                       \
    afr3 = *(const bf16x8*)&As[PAR][48 + row][ASW(quad * 8, row)];                       \
    afr4 = *(const bf16x8*)&As[PAR][row][ASW(32 + quad * 8, row)];                       \
    afr5 = *(const bf16x8*)&As[PAR][16 + row][ASW(32 + quad * 8, row)];                  \
    afr6 = *(const bf16x8*)&As[PAR][32 + row][ASW(32 + quad * 8, row)];                  \
    afr7 = *(const bf16x8*)&As[PAR][48 + row][ASW(32 + quad * 8, row)];                  \
    if ((((P) + 1) & 3) == 0) dW4 = *(float4*)&Tbl[r][((P) + 1) >> 2][1];                \
    WAITVM(12)                                                                           \
    bilin4p(GC0, GC1, GC2, GC3, dW4, &As[PAR ^ 1][r][ASW(qo, r)]);                       \
    bilin4p(GC4, GC5, GC6, GC7, dW4, &As[PAR ^ 1][r][ASW(32 + qo, r)]);                  \
    WAITVM(8)                                                                            \
    MFMA16P                                                                              \
    BARRIER_LGKM                                                                         \
  }

__global__ __launch_bounds__(512, 2) void fused_gemm(const unsigned short* __restrict__ xt,
                                                     const int4* __restrict__ DIW,
                                                     const unsigned short* __restrict__ WB,
                                                     const float* __restrict__ bias,
                                                     float* __restrict__ out) {
  __shared__ unsigned short As[2][64][64];   // 32,768 B, XOR-swizzled columns
  __shared__ int4 Tbl[64][9][2];             // 18,432 B [r][tap]{dI, dW}

  int tid = threadIdx.x;
  int lane = tid & 63, wv = tid >> 6;        // 8 waves
  int mt = (blockIdx.x & 7) * 32 + (blockIdx.x >> 3);   // XCD-chunked swizzle
  int mb = mt * 64;
  int b = mb >> 12;
  int hw0 = mb & 4095;
  const unsigned short* xtb = xt + ((size_t)b << 20);

  // stage index/weight table (1152 int4) — full drain BEFORE any asm loads
  {
    const int4* src = DIW + (size_t)mb * 18;
    int4* dst = (int4*)Tbl;
    for (int i = tid; i < 1152; i += 512)
      gload_lds16(src + i, dst + i);
  }
  __syncthreads();

  int r = tid >> 3;        // sampler row 0..63 (8 threads/row)
  int qo = (tid & 7) * 4;  // sampler channel sub-block (4 ch per tile)

  int4 dI4 = Tbl[r][0][0];
  float4 dW4 = *(float4*)&Tbl[r][0][1];

  int row = lane & 15, quad = lane >> 4;
  const unsigned short* bpb = WB + (size_t)(wv * 2) * 512 + quad * 128 + row * 8;

  f32x4 acc[4][2] = {};
  uint2 gA0, gA1, gA2, gA3, gA4, gA5, gA6, gA7;   // even-period gather set
  uint2 gB0, gB1, gB2, gB3, gB4, gB5, gB6, gB7;   // odd-period gather set
  bf16x8 bB0, bB1, bB2, bB3;
  bf16x8 afr0, afr1, afr2, afr3, afr4, afr5, afr6, afr7;

  // ---- prologue: sample period 0 (tiles 0,1) via compiler loads ----
  {
    uint2 p00 = *(const uint2*)(xtb + dI4.x + qo);
    uint2 p01 = *(const uint2*)(xtb + dI4.y + qo);
    uint2 p10 = *(const uint2*)(xtb + dI4.z + qo);
    uint2 p11 = *(const uint2*)(xtb + dI4.w + qo);
    bilin4p(p00, p01, p10, p11, dW4, &As[0][r][ASW(qo, r)]);
    p00 = *(const uint2*)(xtb + dI4.x + 32 + qo);
    p01 = *(const uint2*)(xtb + dI4.y + 32 + qo);
    p10 = *(const uint2*)(xtb + dI4.z + 32 + qo);
    p11 = *(const uint2*)(xtb + dI4.w + 32 + qo);
    bilin4p(p00, p01, p10, p11, dW4, &As[0][r][ASW(32 + qo, r)]);
    // pinned G for period 1 data (tiles 2,3: ch 64..127, tap 0)
    GLOAD8(gB0, xtb + dI4.x + 64 + qo);
    GLOAD8(gB1, xtb + dI4.y + 64 + qo);
    GLOAD8(gB2, xtb + dI4.z + 64 + qo);
    GLOAD8(gB3, xtb + dI4.w + 64 + qo);
    GLOAD8(gB4, xtb + dI4.x + 96 + qo);
    GLOAD8(gB5, xtb + dI4.y + 96 + qo);
    GLOAD8(gB6, xtb + dI4.z + 96 + qo);
    GLOAD8(gB7, xtb + dI4.w + 96 + qo);
  }
  BARRIER_LGKM   // As[0] visible; 8 asm loads stay in flight

  // ---- steady loop: periods 0..33 ----
#pragma unroll 1
  for (int p = 0; p < 34; p += 2) {
    FITER_P(p,     0, gA0, gA1, gA2, gA3, gA4, gA5, gA6, gA7,
                      gB0, gB1, gB2, gB3, gB4, gB5, gB6, gB7)
    FITER_P(p + 1, 1, gB0, gB1, gB2, gB3, gB4, gB5, gB6, gB7,
                      gA0, gA1, gA2, gA3, gA4, gA5, gA6, gA7)
  }

  // ---- peeled P=34 (PAR=0): period-35 data is in gB (issued at P=33, GI=gB) ----
  {
    const unsigned short* bt0 = bpb + (size_t)68 * 8192;
    GLOAD16(bB0, bt0);
    GLOAD16(bB1, bt0 + 512);
    GLOAD16(bB2, bt0 + 8192);
    GLOAD16(bB3, bt0 + 8192 + 512);
    afr0 = *(const bf16x8*)&As[0][row][ASW(quad * 8, row)];
    afr1 = *(const bf16x8*)&As[0][16 + row][ASW(quad * 8, row)];
    afr2 = *(const bf16x8*)&As[0][32 + row][ASW(quad * 8, row)];
    afr3 = *(const bf16x8*)&As[0][48 + row][ASW(quad * 8, row)];
    afr4 = *(const bf16x8*)&As[0][row][ASW(32 + quad * 8, row)];
    afr5 = *(const bf16x8*)&As[0][16 + row][ASW(32 + quad * 8, row)];
    afr6 = *(const bf16x8*)&As[0][32 + row][ASW(32 + quad * 8, row)];
    afr7 = *(const bf16x8*)&As[0][48 + row][ASW(32 + quad * 8, row)];
    WAITVM(4)
    bilin4p(gB0, gB1, gB2, gB3, dW4, &As[1][r][ASW(qo, r)]);       // dW4 = tap 8
    bilin4p(gB4, gB5, gB6, gB7, dW4, &As[1][r][ASW(32 + qo, r)]);
    WAITVM(0)
    MFMA16P
    BARRIER_LGKM
  }
  // ---- peeled P=35 (PAR=1): last period, no bilin ----
  {
    const unsigned short* bt0 = bpb + (size_t)70 * 8192;
    GLOAD16(bB0, bt0);
    GLOAD16(bB1, bt0 + 512);
    GLOAD16(bB2, bt0 + 8192);
    GLOAD16(bB3, bt0 + 8192 + 512);
    afr0 = *(const bf16x8*)&As[1][row][ASW(quad * 8, row)];
    afr1 = *(const bf16x8*)&As[1][16 + row][ASW(quad * 8, row)];
    afr2 = *(const bf16x8*)&As[1][32 + row][ASW(quad * 8, row)];
    afr3 = *(const bf16x8*)&As[1][48 + row][ASW(quad * 8, row)];
    afr4 = *(const bf16x8*)&As[1][row][ASW(32 + quad * 8, row)];
    afr5 = *(const bf16x8*)&As[1][16 + row][ASW(32 + quad * 8, row)];
    afr6 = *(const bf16x8*)&As[1][32 + row][ASW(32 + quad * 8, row)];
    afr7 = *(const bf16x8*)&As[1][48 + row][ASW(32 + quad * 8, row)];
    WAITVM(0)
    MFMA16P
  }

  // ---- epilogue: add bias, store NCHW ----
#pragma unroll
  for (int j = 0; j < 2; ++j) {
    int o = wv * 32 + j * 16 + row;
    float bo = bias[o];
#pragma unroll
    for (int i = 0; i < 4; ++i) {
      int hw = hw0 + i * 16 + quad * 4;
      float4 v;
      v.x = acc[i][j][0] + bo;
      v.y = acc[i][j][1] + bo;
      v.z = acc[i][j][2] + bo;
      v.w = acc[i][j][3] + bo;
      *(float4*)(out + (((size_t)(b * COUT + o)) << 12) + hw) = v;
    }
  }
}

// ---------------- launch ----------------
extern "C" void kernel_launch(void* const* d_in, const int* in_sizes, int n_in,
                              void* d_out, int out_size, void* d_ws, size_t ws_size,
                              hipStream_t stream) {
  const float* x        = (const float*)d_in[0];
  const float* weight   = (const float*)d_in[1];
  const float* bias     = (const float*)d_in[2];
  const float* p_weight = (const float*)d_in[3];
  const float* p_bias   = (const float*)d_in[4];
  float* out = (float*)d_out;
  char* ws = (char*)d_ws;

  // workspace layout (bytes); total ~31 MB
  const size_t OFF_XT   = 0;                          //  8,388,608  bf16 NHWC x
  const size_t OFF_WB   = OFF_XT + 8388608;           //  1,179,648  bf16 WB2
  const size_t OFF_PW   = OFF_WB + 1179648;           //    147,456  bf16
  const size_t OFF_P    = OFF_PW + 147456;            // 16,777,216  fp32 partials
  const size_t OFF_ZP   = OFF_P + 16777216;           //      8,192  zeropage
  const size_t OFF_DIW  = OFF_ZP + 8192;              //  4,718,592  idx/weight table

  unsigned short* xt    = (unsigned short*)(ws + OFF_XT);
  unsigned short* WB    = (unsigned short*)(ws + OFF_WB);
  unsigned short* PWs   = (unsigned short*)(ws + OFF_PW);
  float* Pbuf           = (float*)(ws + OFF_P);
  unsigned short* zerop = (unsigned short*)(ws + OFF_ZP);
  int4* DIW             = (int4*)(ws + OFF_DIW);

  prep_and_transpose<<<4096 + 2592, 256, 0, stream>>>(x, weight, p_weight, xt, WB, PWs, zerop);
  offset_conv_sk<<<dim3(MTOT / 64, SPLITK), 256, 0, stream>>>(xt, PWs, zerop, Pbuf);
  index_prep<<<576, 256, 0, stream>>>(Pbuf, p_bias, DIW);
  fused_gemm<<<256, 512, 0, stream>>>(xt, DIW, WB, bias, out);
}

// Round 11
// 130.754 us; speedup vs baseline: 1.0482x; 1.0482x over previous
//
#include <hip/hip_runtime.h>
#include <stdint.h>

// DCNv2 forward, MI355X — R22: period-old waits + MFMA-first + 16B gathers.
//  R21 post-mortem: BK=64 + swizzle fixed conflicts (2.95M->590K) but only
//  -7%: per-period cost 3187cy vs ~1200cy overlap floor. Residual = wait
//  stalls: B waited same-period (coverage ~300cy < L2 latency), and bilin
//  blocked MFMA. R22 steady body:
//   issue B(P+1)x4 [GLOAD16] -> alt set; issue G(P+2)x4 [GLOAD16, thread
//   covers 8ch/corner]; ds_read A(P); vmcnt(12) -> 16 MFMA (B(P), period-
//   old); vmcnt(8) -> bilin8 (G(P+1), period-old) writes As[PAR^1];
//   lgkm-only barrier. Every wait target is a full period old => ~0 stall;
//   bilin runs under MFMA latency. Gather instrs halved (8 GLOAD8 ->
//   4 GLOAD16). Ledger: enter 8 [B(P),G(P+1)], +8 issues, 12->MFMA,
//   8->bilin, leave 8. Tail: P=34 vmcnt(8)/(4), P=35 vmcnt(0).
//  K0 prep_and_transpose, K1 offset_conv_sk, K2 index_prep unchanged.

#define CIN 256
#define COUT 256
#define HWS 4096      // H*W
#define MTOT 16384    // B*H*W
#define KTOT 2304     // CIN*9
#define SPLITK 8

typedef __attribute__((ext_vector_type(8))) short bf16x8;
typedef __attribute__((ext_vector_type(4))) float f32x4;

__device__ __forceinline__ unsigned short f2bf(float f) {
  unsigned int u = __float_as_uint(f);
  unsigned int r = (u + 0x7fffu + ((u >> 16) & 1u)) >> 16;
  return (unsigned short)r;
}
__device__ __forceinline__ float bf2f(unsigned short u) {
  return __uint_as_float(((unsigned int)u) << 16);
}
// bf16 pair unpack: 1 VALU each.
__device__ __forceinline__ float bflo(unsigned int u) { return __uint_as_float(u << 16); }
__device__ __forceinline__ float bfhi(unsigned int u) { return __uint_as_float(u & 0xffff0000u); }

__device__ __forceinline__ void gload_lds16(const void* g, void* l) {
  __builtin_amdgcn_global_load_lds((const __attribute__((address_space(1))) void*)g,
                                   (__attribute__((address_space(3))) void*)l, 16, 0, 0);
}

// Issue-pinned loads; completion via manual counted s_waitcnt + sched fence.
#define GLOAD16(D, P) asm volatile("global_load_dwordx4 %0, %1, off" : "=v"(D) : "v"(P))
#define WAITVM(N)                                            \
  {                                                          \
    asm volatile("s_waitcnt vmcnt(" #N ")" ::: "memory");    \
    __builtin_amdgcn_sched_barrier(0);                       \
  }
#define BARRIER_LGKM                                                  \
  { asm volatile("s_waitcnt lgkmcnt(0)\n\ts_barrier" ::: "memory"); }

// As column swizzle: applied identically on write and read (bits 3..5 only,
// so 16B-aligned 8-element runs stay aligned).
#define ASW(c, rr) ((c) ^ (((rr) & 7) << 3))

// ---------------- K0: fused transpose + weight prep (WB2 frag-block order) ----------------
__global__ __launch_bounds__(256) void prep_and_transpose(const float* __restrict__ x,
                                                          const float* __restrict__ w,
                                                          const float* __restrict__ pw,
                                                          unsigned short* __restrict__ xt,
                                                          unsigned short* __restrict__ WB,
                                                          unsigned short* __restrict__ PWs,
                                                          unsigned short* __restrict__ zerop) {
  __shared__ float tile[32][33];
  int bid = blockIdx.x;
  if (bid < 4096) {
    int b = bid >> 10;
    int rest = bid & 1023;
    int hw0 = (rest & 127) * 32;
    int c0 = ((rest >> 7) & 7) * 32;
    int tx = threadIdx.x & 31, ty = threadIdx.x >> 5;
    for (int i = ty; i < 32; i += 8)
      tile[i][tx] = x[(size_t)(b * CIN + c0 + i) * HWS + hw0 + tx];
    __syncthreads();
    for (int r = ty; r < 32; r += 8)
      xt[(size_t)(b * HWS + hw0 + r) * CIN + c0 + tx] = f2bf(tile[tx][r]);
  } else {
    int idx = (bid - 4096) * 256 + threadIdx.x;
    if (idx < 512)
      *(uint4*)(zerop + idx * 8) = make_uint4(0, 0, 0, 0);
    if (idx < KTOT * COUT) {
      // WB2[t][j][quad][row][8]: f = (((t*16+j)*4+quad)*16+row)*8+e
      int f = idx;
      int e = f & 7;
      int row = (f >> 3) & 15;
      int quad = (f >> 7) & 3;
      int j = (f >> 9) & 15;
      int t = f >> 13;                 // 0..71
      int kk = t * 32 + quad * 8 + e;
      int o = j * 16 + row;
      int k = kk >> 8, c = kk & 255;
      WB[f] = f2bf(w[o * KTOT + c * 9 + k]);
    } else {
      int f2 = idx - KTOT * COUT;   // < 2304*32
      int t_ = f2 & 7;
      int rest = f2 >> 3;
      int j = rest & 31;
      int kk = (rest >> 5) * 8 + t_;
      int k = kk >> 8, c = kk & 255;
      float v = (j < 27) ? pw[j * KTOT + c * 9 + k] : 0.0f;
      PWs[f2] = f2bf(v);
    }
  }
}

// ---------------- K1: offset conv, split-K, BM=64 ----------------
__global__ __launch_bounds__(256) void offset_conv_sk(const unsigned short* __restrict__ xt,
                                                      const unsigned short* __restrict__ PWs,
                                                      const unsigned short* __restrict__ zerop,
                                                      float* __restrict__ Pbuf) {
  __shared__ unsigned short Al[64 * 32];   // 4 KB
  __shared__ unsigned short Bl[1024];      // 2 KB
  int tid = threadIdx.x;
  int lane = tid & 63, wv = tid >> 6;
  int mt = (blockIdx.x & 7) * 32 + (blockIdx.x >> 3);   // XCD swizzle
  int m0 = mt * 64;
  int s = blockIdx.y;
  int b = m0 >> 12;
  int hw0 = m0 & 4095;
  f32x4 acc[2] = {};

  for (int tt = 0; tt < 72 / SPLITK; ++tt) {
    int t = s * (72 / SPLITK) + tt;
    int k = t >> 3, c0 = (t & 7) * 32;
    int dyk = k / 3 - 1;
    int dxk = k % 3 - 1;
    __syncthreads();
    if (tid < 128)
      gload_lds16(PWs + (size_t)t * 1024 + tid * 8, &Bl[tid * 8]);
    {
      int r = tid >> 2;
      int hw = hw0 + r;
      int h = hw >> 6, wwp = hw & 63;
      int y = h + dyk, xx = wwp + dxk;
      bool valid = ((unsigned)y < 64u) && ((unsigned)xx < 64u);
      const unsigned short* src = valid
          ? xt + ((size_t)((b << 12) + (y << 6) + xx) << 8) + c0 + (tid & 3) * 8
          : zerop;
      gload_lds16(src, &Al[tid * 8]);
    }
    __syncthreads();
    int row = lane & 15, quad = lane >> 4;
    bf16x8 af = *(const bf16x8*)&Al[(wv * 16 + row) * 32 + quad * 8];
    for (int j = 0; j < 2; ++j) {
      bf16x8 bfr = *(const bf16x8*)&Bl[(quad * 32 + j * 16 + row) * 8];
      acc[j] = __builtin_amdgcn_mfma_f32_16x16x32_bf16(af, bfr, acc[j], 0, 0, 0);
    }
  }

  int row = lane & 15, quad = lane >> 4;
  for (int j = 0; j < 2; ++j) {
    int n = j * 16 + row;
    for (int r_ = 0; r_ < 4; ++r_) {
      int m = m0 + wv * 16 + quad * 4 + r_;
      Pbuf[((size_t)s * MTOT + m) * 32 + n] = acc[j][r_];
    }
  }
}

// ---------------- K2: index prep — reduce Pbuf, compute corner idx + weights ----------------
__global__ __launch_bounds__(256) void index_prep(const float* __restrict__ Pbuf,
                                                  const float* __restrict__ p_bias,
                                                  int4* __restrict__ DIW) {
  int gid = blockIdx.x * 256 + threadIdx.x;   // 0..147455 == 16384*9
  int m = gid / 9;
  int k = gid - m * 9;

  float dy = p_bias[2 * k];
  float dx = p_bias[2 * k + 1];
  float mv = p_bias[18 + k];
#pragma unroll
  for (int s = 0; s < SPLITK; ++s) {
    const float* p = Pbuf + ((size_t)s * MTOT + m) * 32;
    dy += p[2 * k];
    dx += p[2 * k + 1];
    mv += p[18 + k];
  }
  float mk = 1.0f / (1.0f + __expf(-mv));

  int hw = m & 4095, h = hw >> 6, ww = hw & 63;
  float py = (float)(h - 1 + k / 3) + dy;
  float px = (float)(ww - 1 + k % 3) + dx;
  float y0f = floorf(py), x0f = floorf(px);
  float ay = py - y0f, ax = px - x0f;
  int y0 = (int)y0f, x0 = (int)x0f;

  float w00 = (1.f - ay) * (1.f - ax) * mk;
  float w01 = (1.f - ay) * ax * mk;
  float w10 = ay * (1.f - ax) * mk;
  float w11 = ay * ax * mk;

  float vy0 = ((unsigned)y0 < 64u) ? 1.f : 0.f;
  float vy1 = ((unsigned)(y0 + 1) < 64u) ? 1.f : 0.f;
  float vx0 = ((unsigned)x0 < 64u) ? 1.f : 0.f;
  float vx1 = ((unsigned)(x0 + 1) < 64u) ? 1.f : 0.f;
  w00 *= vy0 * vx0; w01 *= vy0 * vx1; w10 *= vy1 * vx0; w11 *= vy1 * vx1;

  int yc0 = min(max(y0, 0), 63), yc1 = min(max(y0 + 1, 0), 63);
  int xc0 = min(max(x0, 0), 63), xc1 = min(max(x0 + 1, 0), 63);

  DIW[(size_t)gid * 2] = make_int4((yc0 * 64 + xc0) * 256, (yc0 * 64 + xc1) * 256,
                                   (yc1 * 64 + xc0) * 256, (yc1 * 64 + xc1) * 256);
  float4 w4 = make_float4(w00, w01, w10, w11);
  ((float4*)DIW)[(size_t)gid * 2 + 1] = w4;
}

// ---------------- K3: fused sample + GEMM — period-old-wait pipeline ----------------
// 512 thr / 8 waves, BM=64, N-split 8 x 32 cols. 36 periods of 2 k-tiles.
// Sampler mapping: r = tid>>3 (row), qo8 = (tid&7)*8 (8 contiguous channels).
__device__ __forceinline__ void bilin8p(const uint4 c00, const uint4 c01,
                                        const uint4 c10, const uint4 c11,
                                        const float4 w4, unsigned short* dst) {
  uint4 o;
  float v0, v1;
  v0 = w4.x * bflo(c00.x) + w4.y * bflo(c01.x) + w4.z * bflo(c10.x) + w4.w * bflo(c11.x);
  v1 = w4.x * bfhi(c00.x) + w4.y * bfhi(c01.x) + w4.z * bfhi(c10.x) + w4.w * bfhi(c11.x);
  o.x = (unsigned)f2bf(v0) | ((unsigned)f2bf(v1) << 16);
  v0 = w4.x * bflo(c00.y) + w4.y * bflo(c01.y) + w4.z * bflo(c10.y) + w4.w * bflo(c11.y);
  v1 = w4.x * bfhi(c00.y) + w4.y * bfhi(c01.y) + w4.z * bfhi(c10.y) + w4.w * bfhi(c11.y);
  o.y = (unsigned)f2bf(v0) | ((unsigned)f2bf(v1) << 16);
  v0 = w4.x * bflo(c00.z) + w4.y * bflo(c01.z) + w4.z * bflo(c10.z) + w4.w * bflo(c11.z);
  v1 = w4.x * bfhi(c00.z) + w4.y * bfhi(c01.z) + w4.z * bfhi(c10.z) + w4.w * bfhi(c11.z);
  o.z = (unsigned)f2bf(v0) | ((unsigned)f2bf(v1) << 16);
  v0 = w4.x * bflo(c00.w) + w4.y * bflo(c01.w) + w4.z * bflo(c10.w) + w4.w * bflo(c11.w);
  v1 = w4.x * bfhi(c00.w) + w4.y * bfhi(c01.w) + w4.z * bfhi(c10.w) + w4.w * bfhi(c11.w);
  o.w = (unsigned)f2bf(v0) | ((unsigned)f2bf(v1) << 16);
  *(uint4*)dst = o;
}

#define MFMA16P(B0, B1, B2, B3)                                                          \
  acc[0][0] = __builtin_amdgcn_mfma_f32_16x16x32_bf16(afr0, B0, acc[0][0], 0, 0, 0);     \
  acc[0][1] = __builtin_amdgcn_mfma_f32_16x16x32_bf16(afr0, B1, acc[0][1], 0, 0, 0);     \
  acc[1][0] = __builtin_amdgcn_mfma_f32_16x16x32_bf16(afr1, B0, acc[1][0], 0, 0, 0);     \
  acc[1][1] = __builtin_amdgcn_mfma_f32_16x16x32_bf16(afr1, B1, acc[1][1], 0, 0, 0);     \
  acc[2][0] = __builtin_amdgcn_mfma_f32_16x16x32_bf16(afr2, B0, acc[2][0], 0, 0, 0);     \
  acc[2][1] = __builtin_amdgcn_mfma_f32_16x16x32_bf16(afr2, B1, acc[2][1], 0, 0, 0);     \
  acc[3][0] = __builtin_amdgcn_mfma_f32_16x16x32_bf16(afr3, B0, acc[3][0], 0, 0, 0);     \
  acc[3][1] = __builtin_amdgcn_mfma_f32_16x16x32_bf16(afr3, B1, acc[3][1], 0, 0, 0);     \
  acc[0][0] = __builtin_amdgcn_mfma_f32_16x16x32_bf16(afr4, B2, acc[0][0], 0, 0, 0);     \
  acc[0][1] = __builtin_amdgcn_mfma_f32_16x16x32_bf16(afr4, B3, acc[0][1], 0, 0, 0);     \
  acc[1][0] = __builtin_amdgcn_mfma_f32_16x16x32_bf16(afr5, B2, acc[1][0], 0, 0, 0);     \
  acc[1][1] = __builtin_amdgcn_mfma_f32_16x16x32_bf16(afr5, B3, acc[1][1], 0, 0, 0);     \
  acc[2][0] = __builtin_amdgcn_mfma_f32_16x16x32_bf16(afr6, B2, acc[2][0], 0, 0, 0);     \
  acc[2][1] = __builtin_amdgcn_mfma_f32_16x16x32_bf16(afr6, B3, acc[2][1], 0, 0, 0);     \
  acc[3][0] = __builtin_amdgcn_mfma_f32_16x16x32_bf16(afr7, B2, acc[3][0], 0, 0, 0);     \
  acc[3][1] = __builtin_amdgcn_mfma_f32_16x16x32_bf16(afr7, B3, acc[3][1], 0, 0, 0);

// Steady period P. GI* receive G(P+2 data); GC* hold G(P+1) (issued at P-1).
// BI* receive B(P+1); BC* hold B(P) (issued at P-1, oldest in flight).
#define FITER_P2(P, PAR, GI0, GI1, GI2, GI3, GC0, GC1, GC2, GC3,                         \
                 BC0, BC1, BC2, BC3, BI0, BI1, BI2, BI3)                                 \
  {                                                                                      \
    const unsigned short* btn = bpb + (size_t)(2 * ((P) + 1)) * 8192;                    \
    GLOAD16(BI0, btn);                                                                   \
    GLOAD16(BI1, btn + 512);                                                             \
    GLOAD16(BI2, btn + 8192);                                                            \
    GLOAD16(BI3, btn + 8192 + 512);                                                      \
    if ((((P) + 2) & 3) == 0) dI4 = Tbl[r][((P) + 2) >> 2][0];                           \
    int cb = ((2 * (P) + 4) & 7) * 32 + qo8;                                             \
    GLOAD16(GI0, xtb + dI4.x + cb);                                                      \
    GLOAD16(GI1, xtb + dI4.y + cb);                                                      \
    GLOAD16(GI2, xtb + dI4.z + cb);                                                      \
    GLOAD16(GI3, xtb + dI4.w + cb);                                                      \
    afr0 = *(const bf16x8*)&As[PAR][row][ASW(quad * 8, row)];                            \
    afr1 = *(const bf16x8*)&As[PAR][16 + row][ASW(quad * 8, row)];                       \
    afr2 = *(const bf16x8*)&As[PAR][32 + row][ASW(quad * 8, row)];                       \
    afr3 = *(const bf16x8*)&As[PAR][48 + row][ASW(quad * 8, row)];                       \
    afr4 = *(const bf16x8*)&As[PAR][row][ASW(32 + quad * 8, row)];                       \
    afr5 = *(const bf16x8*)&As[PAR][16 + row][ASW(32 + quad * 8, row)];                  \
    afr6 = *(const bf16x8*)&As[PAR][32 + row][ASW(32 + quad * 8, row)];                  \
    afr7 = *(const bf16x8*)&As[PAR][48 + row][ASW(32 + quad * 8, row)];                  \
    if ((((P) + 1) & 3) == 0) dW4 = *(float4*)&Tbl[r][((P) + 1) >> 2][1];                \
    WAITVM(12)                                                                           \
    MFMA16P(BC0, BC1, BC2, BC3)                                                          \
    WAITVM(8)                                                                            \
    bilin8p(GC0, GC1, GC2, GC3, dW4, &As[PAR ^ 1][r][ASW(qo8, r)]);                      \
    BARRIER_LGKM                                                                         \
  }

__global__ __launch_bounds__(512, 2) void fused_gemm(const unsigned short* __restrict__ xt,
                                                     const int4* __restrict__ DIW,
                                                     const unsigned short* __restrict__ WB,
                                                     const float* __restrict__ bias,
                                                     float* __restrict__ out) {
  __shared__ unsigned short As[2][64][64];   // 32,768 B, XOR-swizzled columns
  __shared__ int4 Tbl[64][9][2];             // 18,432 B [r][tap]{dI, dW}

  int tid = threadIdx.x;
  int lane = tid & 63, wv = tid >> 6;        // 8 waves
  int mt = (blockIdx.x & 7) * 32 + (blockIdx.x >> 3);   // XCD-chunked swizzle
  int mb = mt * 64;
  int b = mb >> 12;
  int hw0 = mb & 4095;
  const unsigned short* xtb = xt + ((size_t)b << 20);

  // stage index/weight table (1152 int4) — full drain BEFORE any asm loads
  {
    const int4* src = DIW + (size_t)mb * 18;
    int4* dst = (int4*)Tbl;
    for (int i = tid; i < 1152; i += 512)
      gload_lds16(src + i, dst + i);
  }
  __syncthreads();

  int r = tid >> 3;         // sampler row 0..63 (8 threads/row)
  int qo8 = (tid & 7) * 8;  // sampler channel sub-block (8 ch, 16 B)

  int4 dI4 = Tbl[r][0][0];
  float4 dW4 = *(float4*)&Tbl[r][0][1];

  int row = lane & 15, quad = lane >> 4;
  const unsigned short* bpb = WB + (size_t)(wv * 2) * 512 + quad * 128 + row * 8;

  f32x4 acc[4][2] = {};
  uint4 gA0, gA1, gA2, gA3;            // even-period gather set
  uint4 gB0, gB1, gB2, gB3;            // odd-period gather set
  bf16x8 bA0, bA1, bA2, bA3;           // even-period B set
  bf16x8 bB0, bB1, bB2, bB3;           // odd-period B set
  bf16x8 afr0, afr1, afr2, afr3, afr4, afr5, afr6, afr7;

  // ---- prologue: sample period 0 via compiler loads; pin B(0), G(1) ----
  {
    uint4 p00 = *(const uint4*)(xtb + dI4.x + qo8);
    uint4 p01 = *(const uint4*)(xtb + dI4.y + qo8);
    uint4 p10 = *(const uint4*)(xtb + dI4.z + qo8);
    uint4 p11 = *(const uint4*)(xtb + dI4.w + qo8);
    bilin8p(p00, p01, p10, p11, dW4, &As[0][r][ASW(qo8, r)]);
    // pinned issues, ORDER: B(0) x4 first (oldest), then G(1) x4
    GLOAD16(bA0, bpb);
    GLOAD16(bA1, bpb + 512);
    GLOAD16(bA2, bpb + 8192);
    GLOAD16(bA3, bpb + 8192 + 512);
    int cb1 = 64 + qo8;   // period 1 = tiles 2,3 (ch 64..127), tap 0
    GLOAD16(gA0, xtb + dI4.x + cb1);
    GLOAD16(gA1, xtb + dI4.y + cb1);
    GLOAD16(gA2, xtb + dI4.z + cb1);
    GLOAD16(gA3, xtb + dI4.w + cb1);
  }
  BARRIER_LGKM   // As[0] visible; 8 pinned loads in flight

  // ---- steady loop: periods 0..33 ----
#pragma unroll 1
  for (int p = 0; p < 34; p += 2) {
    FITER_P2(p,     0, gB0, gB1, gB2, gB3, gA0, gA1, gA2, gA3,
                       bA0, bA1, bA2, bA3, bB0, bB1, bB2, bB3)
    FITER_P2(p + 1, 1, gA0, gA1, gA2, gA3, gB0, gB1, gB2, gB3,
                       bB0, bB1, bB2, bB3, bA0, bA1, bA2, bA3)
  }

  // ---- peeled P=34 (PAR=0): BC=bA=B(34), GC=gA=G(35); issue B(35)->bB ----
  {
    const unsigned short* btn = bpb + (size_t)70 * 8192;
    GLOAD16(bB0, btn);
    GLOAD16(bB1, btn + 512);
    GLOAD16(bB2, btn + 8192);
    GLOAD16(bB3, btn + 8192 + 512);
    afr0 = *(const bf16x8*)&As[0][row][ASW(quad * 8, row)];
    afr1 = *(const bf16x8*)&As[0][16 + row][ASW(quad * 8, row)];
    afr2 = *(const bf16x8*)&As[0][32 + row][ASW(quad * 8, row)];
    afr3 = *(const bf16x8*)&As[0][48 + row][ASW(quad * 8, row)];
    afr4 = *(const bf16x8*)&As[0][row][ASW(32 + quad * 8, row)];
    afr5 = *(const bf16x8*)&As[0][16 + row][ASW(32 + quad * 8, row)];
    afr6 = *(const bf16x8*)&As[0][32 + row][ASW(32 + quad * 8, row)];
    afr7 = *(const bf16x8*)&As[0][48 + row][ASW(32 + quad * 8, row)];
    WAITVM(8)    // drains B(34)
    MFMA16P(bA0, bA1, bA2, bA3)
    WAITVM(4)    // drains G(35)
    bilin8p(gA0, gA1, gA2, gA3, dW4, &As[1][r][ASW(qo8, r)]);   // dW4 = tap 8
    BARRIER_LGKM
  }
  // ---- peeled P=35 (PAR=1): BC=bB=B(35); no bilin ----
  {
    afr0 = *(const bf16x8*)&As[1][row][ASW(quad * 8, row)];
    afr1 = *(const bf16x8*)&As[1][16 + row][ASW(quad * 8, row)];
    afr2 = *(const bf16x8*)&As[1][32 + row][ASW(quad * 8, row)];
    afr3 = *(const bf16x8*)&As[1][48 + row][ASW(quad * 8, row)];
    afr4 = *(const bf16x8*)&As[1][row][ASW(32 + quad * 8, row)];
    afr5 = *(const bf16x8*)&As[1][16 + row][ASW(32 + quad * 8, row)];
    afr6 = *(const bf16x8*)&As[1][32 + row][ASW(32 + quad * 8, row)];
    afr7 = *(const bf16x8*)&As[1][48 + row][ASW(32 + quad * 8, row)];
    WAITVM(0)
    MFMA16P(bB0, bB1, bB2, bB3)
  }

  // ---- epilogue: add bias, store NCHW ----
#pragma unroll
  for (int j = 0; j < 2; ++j) {
    int o = wv * 32 + j * 16 + row;
    float bo = bias[o];
#pragma unroll
    for (int i = 0; i < 4; ++i) {
      int hw = hw0 + i * 16 + quad * 4;
      float4 v;
      v.x = acc[i][j][0] + bo;
      v.y = acc[i][j][1] + bo;
      v.z = acc[i][j][2] + bo;
      v.w = acc[i][j][3] + bo;
      *(float4*)(out + (((size_t)(b * COUT + o)) << 12) + hw) = v;
    }
  }
}

// ---------------- launch ----------------
extern "C" void kernel_launch(void* const* d_in, const int* in_sizes, int n_in,
                              void* d_out, int out_size, void* d_ws, size_t ws_size,
                              hipStream_t stream) {
  const float* x        = (const float*)d_in[0];
  const float* weight   = (const float*)d_in[1];
  const float* bias     = (const float*)d_in[2];
  const float* p_weight = (const float*)d_in[3];
  const float* p_bias   = (const float*)d_in[4];
  float* out = (float*)d_out;
  char* ws = (char*)d_ws;

  // workspace layout (bytes); total ~31 MB
  const size_t OFF_XT   = 0;                          //  8,388,608  bf16 NHWC x
  const size_t OFF_WB   = OFF_XT + 8388608;           //  1,179,648  bf16 WB2
  const size_t OFF_PW   = OFF_WB + 1179648;           //    147,456  bf16
  const size_t OFF_P    = OFF_PW + 147456;            // 16,777,216  fp32 partials
  const size_t OFF_ZP   = OFF_P + 16777216;           //      8,192  zeropage
  const size_t OFF_DIW  = OFF_ZP + 8192;              //  4,718,592  idx/weight table

  unsigned short* xt    = (unsigned short*)(ws + OFF_XT);
  unsigned short* WB    = (unsigned short*)(ws + OFF_WB);
  unsigned short* PWs   = (unsigned short*)(ws + OFF_PW);
  float* Pbuf           = (float*)(ws + OFF_P);
  unsigned short* zerop = (unsigned short*)(ws + OFF_ZP);
  int4* DIW             = (int4*)(ws + OFF_DIW);

  prep_and_transpose<<<4096 + 2592, 256, 0, stream>>>(x, weight, p_weight, xt, WB, PWs, zerop);
  offset_conv_sk<<<dim3(MTOT / 64, SPLITK), 256, 0, stream>>>(xt, PWs, zerop, Pbuf);
  index_prep<<<576, 256, 0, stream>>>(Pbuf, p_bias, DIW);
  fused_gemm<<<256, 512, 0, stream>>>(xt, DIW, WB, bias, out);
}